// Round 2
// baseline (2456.690 us; speedup 1.0000x reference)
//
#include <hip/hip_runtime.h>

#define NV    50000
#define NRAD  5
#define NANG  8
#define FEAT  64
#define NTPL  64
#define NXY   (NRAD*NANG)      // 40
#define KDIM  (NXY*FEAT)       // 2560

#define TM 64
#define TN 128
#define BLK 256

// W2[(xy*64+f)*N + (o*64+t)] = sum_{r,a} kern[r,a,x,y] * NW[t, r, (a+o*delta)%8, f]
__global__ void build_w2_kernel(const float* __restrict__ kern,
                                const float* __restrict__ nw,
                                const int* __restrict__ deltap,
                                float* __restrict__ w2,
                                int N) {
    int p = blockIdx.x * blockDim.x + threadIdx.x;
    int total = KDIM * N;
    if (p >= total) return;
    int n  = p % N;          // n = o*64 + t
    int kd = p / N;          // kd = xy*64 + f
    int t  = n % NTPL;
    int o  = n / NTPL;
    int f  = kd % FEAT;
    int xy = kd / FEAT;
    int x  = xy / NANG;
    int y  = xy % NANG;
    int delta = deltap[0];
    int ob = o * delta;
    float acc = 0.f;
#pragma unroll
    for (int r = 0; r < NRAD; ++r) {
#pragma unroll
        for (int a = 0; a < NANG; ++a) {
            int a2 = (a + ob) & (NANG - 1);
            acc += kern[((r*NANG + a)*NRAD + x)*NANG + y]
                 * nw[((t*NRAD + r)*NANG + a2)*FEAT + f];
        }
    }
    w2[p] = acc;
}

__launch_bounds__(BLK, 3)
__global__ void conv_main_kernel(const float* __restrict__ mesh,
                                 const int* __restrict__ bidx,
                                 const float* __restrict__ bw,
                                 const float* __restrict__ w2,
                                 const float* __restrict__ sw,
                                 const float* __restrict__ bias,
                                 float* __restrict__ out,
                                 int N) {
    __shared__ float sA[FEAT][TM + 4];   // [f][vertex]  (transposed interp tile)
    __shared__ float sB[FEAT][TN + 4];   // [f][n_local] (W2 tile; also reused for SW^T in phase 0)

    const int tid = threadIdx.x;
    const int n0 = blockIdx.x * TN;
    const int k0 = blockIdx.y * TM;

    const int tn = tid & 31;             // col group: cols tn*4 .. tn*4+3
    const int mg = tid >> 5;             // row group: rows mg*8 .. mg*8+7

    const int vS = tid & 63;             // staging: vertex handled by this thread
    const int fS = (tid >> 6) * 16;      // staging: feature chunk start

    float acc[8][4];

    int tcol[4];
#pragma unroll
    for (int j = 0; j < 4; ++j) tcol[j] = (n0 + tn*4 + j) % NTPL;

    // ---------------- phase 0: acc = bias + center (SW @ mesh_row) ----------------
    {
        // stage SW transposed into sB storage: swl[f*64 + t]
        float* swl = &sB[0][0];
#pragma unroll
        for (int c = 0; c < 16; ++c) {
            int e = tid * 16 + c;            // e = t*64 + f, covers 4096
            int t = e >> 6;
            int f = e & 63;
            swl[f * NTPL + t] = sw[e];
        }
        // stage this block's mesh rows transposed into sA[f][v]
        {
            int k = k0 + vS; if (k >= NV) k = NV - 1;
            const float4* src = (const float4*)(mesh + (long)k * FEAT + fS);
#pragma unroll
            for (int c = 0; c < 4; ++c) {
                float4 mv = src[c];
                sA[fS + 4*c + 0][vS] = mv.x;
                sA[fS + 4*c + 1][vS] = mv.y;
                sA[fS + 4*c + 2][vS] = mv.z;
                sA[fS + 4*c + 3][vS] = mv.w;
            }
        }
        __syncthreads();

        float bv[4];
#pragma unroll
        for (int j = 0; j < 4; ++j) bv[j] = bias[tcol[j]];
#pragma unroll
        for (int mi = 0; mi < 8; ++mi)
#pragma unroll
            for (int j = 0; j < 4; ++j) acc[mi][j] = bv[j];

        for (int f = 0; f < FEAT; ++f) {
            float wv[4];
#pragma unroll
            for (int j = 0; j < 4; ++j) wv[j] = swl[f * NTPL + tcol[j]];
            float av[8];
#pragma unroll
            for (int mi = 0; mi < 8; ++mi) av[mi] = sA[f][mg*8 + mi];
#pragma unroll
            for (int mi = 0; mi < 8; ++mi)
#pragma unroll
                for (int j = 0; j < 4; ++j)
                    acc[mi][j] += av[mi] * wv[j];
        }
    }

    // ---------------- main loop: 40 xy slices, K-chunk = 64 feats ----------------
    for (int xy = 0; xy < NXY; ++xy) {
        __syncthreads();   // previous phase readers done before restaging

        // stage interp tile -> sA[f][v]:  interp = sum_i w_i * mesh[idx_i]
        {
            int k = k0 + vS; if (k >= NV) k = NV - 1;
            long base = ((long)k * NXY + xy) * 3;
            int   i0 = bidx[base+0], i1 = bidx[base+1], i2 = bidx[base+2];
            float w0 = bw[base+0],   w1 = bw[base+1],   w2v = bw[base+2];
            const float4* p0 = (const float4*)(mesh + (long)i0 * FEAT + fS);
            const float4* p1 = (const float4*)(mesh + (long)i1 * FEAT + fS);
            const float4* p2 = (const float4*)(mesh + (long)i2 * FEAT + fS);
#pragma unroll
            for (int c = 0; c < 4; ++c) {
                float4 a = p0[c], b = p1[c], d = p2[c];
                sA[fS + 4*c + 0][vS] = w0*a.x + w1*b.x + w2v*d.x;
                sA[fS + 4*c + 1][vS] = w0*a.y + w1*b.y + w2v*d.y;
                sA[fS + 4*c + 2][vS] = w0*a.z + w1*b.z + w2v*d.z;
                sA[fS + 4*c + 3][vS] = w0*a.w + w1*b.w + w2v*d.w;
            }
        }
        // stage W2 tile -> sB[f][n_local]
        {
            int r  = tid & 63;           // row (feat within slice)
            int ch = tid >> 6;           // col chunk of 32
            const float* src = w2 + (long)(xy*FEAT + r) * N + n0 + ch*32;
            float* dst = &sB[r][ch*32];
#pragma unroll
            for (int c = 0; c < 8; ++c) {
                ((float4*)dst)[c] = ((const float4*)src)[c];
            }
        }
        __syncthreads();

        // 64 k-steps of 8x4 outer product per thread
#pragma unroll 4
        for (int kk = 0; kk < FEAT; ++kk) {
            float4 alo = *(const float4*)&sA[kk][mg*8 + 0];
            float4 ahi = *(const float4*)&sA[kk][mg*8 + 4];
            float4 b   = *(const float4*)&sB[kk][tn*4];
            float av[8] = {alo.x, alo.y, alo.z, alo.w, ahi.x, ahi.y, ahi.z, ahi.w};
            float bv[4] = {b.x, b.y, b.z, b.w};
#pragma unroll
            for (int mi = 0; mi < 8; ++mi)
#pragma unroll
                for (int j = 0; j < 4; ++j)
                    acc[mi][j] += av[mi] * bv[j];
        }
    }

    // ---------------- epilogue: ReLU + store ----------------
#pragma unroll
    for (int mi = 0; mi < 8; ++mi) {
        int k = k0 + mg*8 + mi;
        if (k < NV) {
            float4 r;
            r.x = fmaxf(acc[mi][0], 0.f);
            r.y = fmaxf(acc[mi][1], 0.f);
            r.z = fmaxf(acc[mi][2], 0.f);
            r.w = fmaxf(acc[mi][3], 0.f);
            *(float4*)(out + (long)k * N + n0 + tn*4) = r;
        }
    }
}

extern "C" void kernel_launch(void* const* d_in, const int* in_sizes, int n_in,
                              void* d_out, int out_size, void* d_ws, size_t ws_size,
                              hipStream_t stream) {
    const float* mesh   = (const float*)d_in[0];
    const int*   bidx   = (const int*)d_in[1];
    const float* bw     = (const float*)d_in[2];
    const float* kern   = (const float*)d_in[3];
    const float* nw     = (const float*)d_in[4];
    const float* sw     = (const float*)d_in[5];
    const float* bias   = (const float*)d_in[6];
    const int*   deltap = (const int*)d_in[7];

    int N = out_size / NV;               // O * 64  (O derived from output size)
    float* w2 = (float*)d_ws;            // KDIM * N floats (5.24 MB at O=8)

    int total = KDIM * N;
    build_w2_kernel<<<(total + 255)/256, 256, 0, stream>>>(kern, nw, deltap, w2, N);

    dim3 grid((N + TN - 1)/TN, (NV + TM - 1)/TM);
    conv_main_kernel<<<grid, BLK, 0, stream>>>(mesh, bidx, bw, w2, sw, bias,
                                               (float*)d_out, N);
}